// Round 1
// baseline (184.931 us; speedup 1.0000x reference)
//
#include <hip/hip_runtime.h>
#include <stdint.h>

// MS-SSIM + L1 fused loss, MI355X.
// R12: shrink XQ from 5 staged planes to 2 (x, y) and derive the x^2, y^2,
// x*y H-pass A-fragments in registers, hoisted once per channel and reused
// across that channel's sigma passes (fragment addressing is sigma-invariant).
// R11 counters: 2 blocks/CU (LDS 74.7KB) -> latency-bound (occupancy 20%,
// no pipe >50%). This cuts LDS to ~47KB -> 3 blocks/CU, removes ~58 b128
// reads + 36 b64 writes per thread, VALU ~neutral (derivation replaces
// staging packs). VGPR capped via __launch_bounds__(NT,3) to keep 3 waves/EU.
// Everything else is R10/R11 (verified).

#define TILE 32
#define HALO 16
#define SSTR 72            // bf16 stride (144B row, 16B-multiple)
#define PLN  (64 * SSTR)
#define PTPLN (32 * SSTR)
#define NT   256

#define C1c 1.0e-4f
#define C2c 9.0e-4f

typedef short bf16x8 __attribute__((ext_vector_type(8)));
typedef float f32x4  __attribute__((ext_vector_type(4)));
typedef unsigned short ush;

// ---- compile-time 1/sum of the 33-tap gaussian ----
constexpr double cexp(double xx) {
  if (xx < -700.0) return 0.0;
  const double ln2 = 0.6931471805599453, il2 = 1.4426950408889634;
  double kd = xx * il2;
  long long k = (long long)(kd + (kd >= 0 ? 0.5 : -0.5));
  double r = xx - (double)k * ln2;
  double t = 1.0, s = 1.0;
  for (int i = 1; i <= 22; ++i) { t *= r / (double)i; s += t; }
  double p = 1.0, base = (k >= 0) ? 2.0 : 0.5;
  long long n = (k >= 0) ? k : -k;
  while (n) { if (n & 1) p *= base; base *= base; n >>= 1; }
  return s * p;
}
constexpr float gsi(double sigma) {
  double inv = 1.0 / (2.0 * sigma * sigma);
  double s = 0.0;
  for (int k = -16; k <= 16; ++k) s += cexp(-(double)(k * k) * inv);
  return (float)(1.0 / s);
}
constexpr float SI05 = gsi(0.5), SI10 = gsi(1.0), SI20 = gsi(2.0),
                SI40 = gsi(4.0), SI80 = gsi(8.0);

// pack two f32 -> bf16x2 (round-half-up)
__device__ __forceinline__ unsigned f2bf_pk(float lo, float hi) {
  union { float f; unsigned u; } a, b; a.f = lo; b.f = hi;
  return __builtin_amdgcn_perm(b.u + 0x8000u, a.u + 0x8000u, 0x07060302u);
}
__device__ __forceinline__ ush f2bf1(float f) {
  union { float f; unsigned u; } c; c.f = f;
  return (ush)((c.u + 0x8000u) >> 16);
}

struct WFrag {
  bf16x8 h[2][2];   // [nt][kchunk] : H-pass B-operand
  bf16x8 v[2];      // [kchunk]     : V-pass A-operand (t = wave>>1 baked in)
};

// Fill WM[m][k] = wf5[SIG][k-m] (k-m in [0,32] else 0), then load frags.
template<int SIG>
__device__ __forceinline__ void build_wm(ush* __restrict__ WM,
                                         const float (*__restrict__ wf5)[40],
                                         int tid, int wave, int lane,
                                         WFrag& W) {
  __syncthreads();                 // prior WM/frag/PT readers + staged XQ ordered
  #pragma unroll
  for (int i = 0; i < 8; ++i) {
    const int idx = i * 256 + tid;         // 0..2047
    const int m = idx >> 6, k = idx & 63;
    const int t = k - m;
    const int tc = t < 0 ? 0 : (t > 32 ? 32 : t);
    float v = wf5[SIG][tc];
    v = (t >= 0 && t <= 32) ? v : 0.f;
    WM[m * SSTR + k] = f2bf1(v);
  }
  __syncthreads();                 // WM ready
  const int l16 = lane & 15, quad = lane >> 4;
  #pragma unroll
  for (int t = 0; t < 2; ++t)
    #pragma unroll
    for (int c = 0; c < 2; ++c)
      W.h[t][c] = *(const bf16x8*)(WM + (t * 16 + l16) * SSTR + quad * 8 + 32 * c);
  const int sv0 = (wave >> 1) * 16;
  W.v[0] = *(const bf16x8*)(WM + (sv0 + l16) * SSTR + quad * 8);
  W.v[1] = *(const bf16x8*)(WM + (sv0 + l16) * SSTR + quad * 8 + 32);
}

// One separable conv pass via two banded GEMMs; A-fragments from registers,
// weights from registers. Caller must ensure a barrier ordered prior PT
// readers before entry (H stage writes PT immediately).
template<int NQ>
__device__ __forceinline__ void conv_pass(const bf16x8 (&A)[NQ][2],
                                          const WFrag& W,
                                          ush* __restrict__ PT,
                                          int wave, int lane, f32x4* V) {
  const int l16 = lane & 15, quad = lane >> 4;
  const int m0 = wave * 16;
  // H-GEMM: D(64x32) = A(64x64) x Wh; store transposed bf16 into PT
  #pragma unroll
  for (int q = 0; q < NQ; ++q) {
    #pragma unroll
    for (int nt = 0; nt < 2; ++nt) {
      f32x4 acc = {0.f, 0.f, 0.f, 0.f};
      acc = __builtin_amdgcn_mfma_f32_16x16x32_bf16(A[q][0], W.h[nt][0], acc, 0, 0, 0);
      acc = __builtin_amdgcn_mfma_f32_16x16x32_bf16(A[q][1], W.h[nt][1], acc, 0, 0, 0);
      uint2 u;
      u.x = f2bf_pk(acc[0], acc[1]);
      u.y = f2bf_pk(acc[2], acc[3]);
      *(uint2*)(PT + q * PTPLN + (nt * 16 + l16) * SSTR + m0 + quad * 4) = u;
    }
  }
  __syncthreads();                 // PT complete
  // V-GEMM: D(32x32) = Wv(32x64) x P
  const int n0 = (wave & 1) * 16;
  #pragma unroll
  for (int q = 0; q < NQ; ++q) {
    const ush* pp = PT + q * PTPLN + (n0 + l16) * SSTR + quad * 8;
    const bf16x8 b0 = *(const bf16x8*)pp;
    const bf16x8 b1 = *(const bf16x8*)(pp + 32);
    f32x4 acc = {0.f, 0.f, 0.f, 0.f};
    acc = __builtin_amdgcn_mfma_f32_16x16x32_bf16(W.v[0], b0, acc, 0, 0, 0);
    acc = __builtin_amdgcn_mfma_f32_16x16x32_bf16(W.v[1], b1, acc, 0, 0, 0);
    V[q] = acc;
  }
}

// SSIM epilogue on V[5]
__device__ __forceinline__ void ssim_fold(const f32x4* V, int mult, bool last,
                                          float* PIcs) {
  #pragma unroll
  for (int r = 0; r < 4; ++r) {
    const float mux = V[0][r], muy = V[1][r];
    const float A = mux * muy;
    const float Bq = mux * mux + muy * muy;
    const float S = V[2][r] + V[3][r] - Bq;
    const float sxy = V[4][r] - A;
    const float cs = (2.f * sxy + C2c) * __builtin_amdgcn_rcpf(S + C2c);
    float p = cs;
    if (mult >= 2) p *= cs;
    if (mult >= 3) p *= cs;
    if (last) {
      const float l = (2.f * A + C1c) * __builtin_amdgcn_rcpf(Bq + C1c);
      p *= l * l * l;
    }
    PIcs[r] *= p;
  }
}

__global__ __launch_bounds__(NT, 3)
void msssim_fused_kernel(const float* __restrict__ x, const float* __restrict__ y,
                         const float* __restrict__ disc,
                         float* __restrict__ partials) {
  __shared__ ush XQ[2 * PLN];      // planes: x, y  (plane0 reused for SAD at end)
  __shared__ ush PT[5 * PTPLN];
  __shared__ ush WM[32 * SSTR];
  __shared__ float wf5[5][40];
  __shared__ float red[12];

  const int tid = threadIdx.x;
  const int wave = tid >> 6, lane = tid & 63;
  const int bx = blockIdx.x, by = blockIdx.y, b = blockIdx.z;
  const int x0 = bx * TILE - HALO, y0 = by * TILE - HALO;
  const int blk = (b * 16 + by) * 16 + bx;

  // disc^2 partial (16 elems/block), issued early so latency hides
  float d2 = 0.f;
  { const int di = blk * 16 + tid;
    if (tid < 16 && di < 8 * 62 * 62) { const float dd = disc[di] - 1.f; d2 = dd * dd; } }

  // one-time tap tables (first build_wm's leading barrier orders readers)
  if (tid < 165) {
    const int sig = tid / 33;
    const int k = tid - sig * 33;
    const float d = (float)(k - 16);
    float inv, si;
    if (sig == 0)      { inv = 2.0f;       si = SI05; }
    else if (sig == 1) { inv = 0.5f;       si = SI10; }
    else if (sig == 2) { inv = 0.125f;     si = SI20; }
    else if (sig == 3) { inv = 0.03125f;   si = SI40; }
    else               { inv = 0.0078125f; si = SI80; }
    wf5[sig][k] = __expf(-d * d * inv) * si;
  }

  const int sr = tid >> 4;           // staging row within 16-row band
  const int sc = (tid & 15) * 4;     // staging col group

  float4 PX[4], PY[4];
  auto issue_loads = [&](int ch) {
    const float* __restrict__ xs = x + (size_t)(b * 3 + ch) * 262144;
    const float* __restrict__ ys = y + (size_t)(b * 3 + ch) * 262144;
    #pragma unroll
    for (int it = 0; it < 4; ++it) {
      const int r = it * 16 + sr;
      const int gy = y0 + r, gx = x0 + sc;
      const bool rowok = (gy >= 0) && (gy < 512);
      if (rowok && gx >= 0 && gx <= 508) {
        PX[it] = *(const float4*)(xs + gy * 512 + gx);
        PY[it] = *(const float4*)(ys + gy * 512 + gx);
      } else {
        float tx[4], ty[4];
        #pragma unroll
        for (int e = 0; e < 4; ++e) {
          const int g = gx + e;
          const bool ok = rowok && (g >= 0) && (g < 512);
          tx[e] = ok ? xs[gy * 512 + g] : 0.f;
          ty[e] = ok ? ys[gy * 512 + g] : 0.f;
        }
        PX[it] = make_float4(tx[0], tx[1], tx[2], tx[3]);
        PY[it] = make_float4(ty[0], ty[1], ty[2], ty[3]);
      }
    }
  };

  float PIcs[4] = {1.f, 1.f, 1.f, 1.f};
  float sad[4][4];                    // sum over channels of |x-y|, 16 px/thread
  #pragma unroll
  for (int it = 0; it < 4; ++it)
    #pragma unroll
    for (int e = 0; e < 4; ++e) sad[it][e] = 0.f;

  issue_loads(0);

  // ---- staging helper: 2 planes (x, y) + SAD accumulation ----
  auto stage = [&]() {
    #pragma unroll
    for (int it = 0; it < 4; ++it) {
      const int r = it * 16 + sr;
      float xv[4] = {PX[it].x, PX[it].y, PX[it].z, PX[it].w};
      float yv[4] = {PY[it].x, PY[it].y, PY[it].z, PY[it].w};
      #pragma unroll
      for (int e = 0; e < 4; ++e) {
        xv[e] = fmaf(xv[e], 0.5f, 0.5f);
        yv[e] = fmaf(yv[e], 0.5f, 0.5f);
        sad[it][e] += fabsf(xv[e] - yv[e]);
      }
      const int off = r * SSTR + sc;
      *(uint2*)(XQ + 0 * PLN + off) = make_uint2(f2bf_pk(xv[0], xv[1]), f2bf_pk(xv[2], xv[3]));
      *(uint2*)(XQ + 1 * PLN + off) = make_uint2(f2bf_pk(yv[0], yv[1]), f2bf_pk(yv[2], yv[3]));
    }
  };

  f32x4 V[5];
  WFrag W;
  bf16x8 AF[5][2];   // per-channel A-fragments: x, y, x^2, y^2, xy

  // ---- load x/y A-frags from staged XQ, derive squared planes in regs ----
  // Caller must ensure a barrier ordered the XQ stores before this.
  auto load_derive = [&]() {
    const int l16 = lane & 15, quad = lane >> 4;
    const ush* xp = XQ + (wave * 16 + l16) * SSTR + quad * 8;
    AF[0][0] = *(const bf16x8*)xp;
    AF[0][1] = *(const bf16x8*)(xp + 32);
    AF[1][0] = *(const bf16x8*)(xp + PLN);
    AF[1][1] = *(const bf16x8*)(xp + PLN + 32);
    #pragma unroll
    for (int c = 0; c < 2; ++c) {
      float xf[8], yf[8];
      #pragma unroll
      for (int e = 0; e < 8; ++e) {
        union { unsigned u; float f; } ax, ay;
        ax.u = ((unsigned)(ush)AF[0][c][e]) << 16;
        ay.u = ((unsigned)(ush)AF[1][c][e]) << 16;
        xf[e] = ax.f; yf[e] = ay.f;
      }
      union { unsigned u[4]; bf16x8 v; } w2, w3, w4;
      #pragma unroll
      for (int p = 0; p < 4; ++p) {
        w2.u[p] = f2bf_pk(xf[2*p] * xf[2*p], xf[2*p+1] * xf[2*p+1]);
        w3.u[p] = f2bf_pk(yf[2*p] * yf[2*p], yf[2*p+1] * yf[2*p+1]);
        w4.u[p] = f2bf_pk(xf[2*p] * yf[2*p], xf[2*p+1] * yf[2*p+1]);
      }
      AF[2][c] = w2.v; AF[3][c] = w3.v; AF[4][c] = w4.v;
    }
  };

  // ======== ch0: sigma 0.5 (x3), sigma 1 (x2) ========
  stage();
  issue_loads(1);
  build_wm<0>(WM, wf5, tid, wave, lane, W);     // leading barrier orders XQ too
  load_derive();
  conv_pass<5>(AF, W, PT, wave, lane, V);
  ssim_fold(V, 3, false, PIcs);
  build_wm<1>(WM, wf5, tid, wave, lane, W);
  conv_pass<5>(AF, W, PT, wave, lane, V);       // AF reused
  ssim_fold(V, 2, false, PIcs);

  // ======== ch1: sigma 1 (x1, W reused), sigma 2 (x3), sigma 4 (x1) ======
  stage();
  issue_loads(2);
  __syncthreads();                              // XQ staged; prior PT readers done
  load_derive();
  conv_pass<5>(AF, W, PT, wave, lane, V);
  ssim_fold(V, 1, false, PIcs);
  build_wm<2>(WM, wf5, tid, wave, lane, W);
  conv_pass<5>(AF, W, PT, wave, lane, V);       // AF reused
  ssim_fold(V, 3, false, PIcs);
  build_wm<3>(WM, wf5, tid, wave, lane, W);
  conv_pass<5>(AF, W, PT, wave, lane, V);       // AF reused
  ssim_fold(V, 1, false, PIcs);

  // ======== ch2: sigma 4 (x2, W reused), sigma 8 (x3 + l^3) ========
  stage();
  __syncthreads();                              // XQ staged; prior PT readers done
  load_derive();
  conv_pass<5>(AF, W, PT, wave, lane, V);
  ssim_fold(V, 2, false, PIcs);
  build_wm<4>(WM, wf5, tid, wave, lane, W);
  conv_pass<5>(AF, W, PT, wave, lane, V);       // AF reused
  ssim_fold(V, 3, true, PIcs);

  // ======== deferred gaussian L1: conv(SAD, sigma 8) (W frags reused) ========
  #pragma unroll
  for (int it = 0; it < 4; ++it) {
    const int off = (it * 16 + sr) * SSTR + sc;
    *(uint2*)(XQ + off) =
        make_uint2(f2bf_pk(sad[it][0], sad[it][1]), f2bf_pk(sad[it][2], sad[it][3]));
  }
  __syncthreads();                              // SAD plane staged; PT readers done
  bf16x8 SF[1][2];
  {
    const ush* sp = XQ + (wave * 16 + (lane & 15)) * SSTR + (lane >> 4) * 8;
    SF[0][0] = *(const bf16x8*)sp;
    SF[0][1] = *(const bf16x8*)(sp + 32);
  }
  f32x4 V1[1];
  conv_pass<1>(SF, W, PT, wave, lane, V1);

  // absacc = central sum of SAD regs (rows 16..47 are it=1,2; cols via sc)
  float absacc = 0.f;
  if (sc >= 16 && sc < 48) {
    #pragma unroll
    for (int it = 1; it <= 2; ++it)
      #pragma unroll
      for (int e = 0; e < 4; ++e) absacc += sad[it][e];
  }

  float mixsum = 0.f;
  #pragma unroll
  for (int r = 0; r < 4; ++r) {
    const float ssim = 1.f - PIcs[r];
    mixsum += 200.f * (0.025f * ssim + 0.975f * (V1[0][r] * (1.f / 3.f)));
  }

  #pragma unroll
  for (int off = 32; off > 0; off >>= 1) {
    mixsum += __shfl_down(mixsum, off);
    absacc += __shfl_down(absacc, off);
    d2     += __shfl_down(d2, off);
  }
  if (lane == 0) { red[wave] = mixsum; red[4 + wave] = absacc; red[8 + wave] = d2; }
  __syncthreads();
  if (tid == 0) {
    float m = 0.f, a = 0.f, d = 0.f;
    #pragma unroll
    for (int i = 0; i < 4; ++i) { m += red[i]; a += red[4 + i]; d += red[8 + i]; }
    partials[3 * blk + 0] = m;
    partials[3 * blk + 1] = a;
    partials[3 * blk + 2] = d;
  }
}

__global__ __launch_bounds__(512)
void msssim_final_kernel(const float* __restrict__ partials,
                         float* __restrict__ out) {
  __shared__ float red[24];
  const int tid = threadIdx.x;
  float m = 0.f, a = 0.f, d2 = 0.f;
  for (int j = tid; j < 2048; j += 512) {
    m  += partials[3 * j + 0];
    a  += partials[3 * j + 1];
    d2 += partials[3 * j + 2];
  }
  #pragma unroll
  for (int off = 32; off > 0; off >>= 1) {
    m  += __shfl_down(m, off);
    a  += __shfl_down(a, off);
    d2 += __shfl_down(d2, off);
  }
  const int wave = tid >> 6, lane = tid & 63;
  if (lane == 0) { red[wave] = m; red[8 + wave] = a; red[16 + wave] = d2; }
  __syncthreads();
  if (tid == 0) {
    float sm = 0.f, sa = 0.f, sd = 0.f;
    #pragma unroll
    for (int i = 0; i < 8; ++i) { sm += red[i]; sa += red[8 + i]; sd += red[16 + i]; }
    const float mix_mean  = sm / (8.f * 512.f * 512.f);
    const float abs_mean  = sa / (8.f * 3.f * 512.f * 512.f);
    const float disc_mean = sd / (8.f * 62.f * 62.f);
    out[0] = 0.5f * (mix_mean + 100.f * abs_mean + disc_mean);
  }
}

extern "C" void kernel_launch(void* const* d_in, const int* in_sizes, int n_in,
                              void* d_out, int out_size, void* d_ws, size_t ws_size,
                              hipStream_t stream) {
  const float* x    = (const float*)d_in[0];
  const float* y    = (const float*)d_in[1];
  const float* disc = (const float*)d_in[2];
  // d_in[3] = g_masks (unused: weights recomputed on device)
  float* partials = (float*)d_ws;   // 2048*3 floats, fully overwritten each call
  dim3 grid(16, 16, 8);
  msssim_fused_kernel<<<grid, NT, 0, stream>>>(x, y, disc, partials);
  msssim_final_kernel<<<1, 512, 0, stream>>>(partials, (float*)d_out);
}

// Round 2
// 143.906 us; speedup vs baseline: 1.2851x; 1.2851x over previous
//
#include <hip/hip_runtime.h>
#include <stdint.h>

// MS-SSIM + L1 fused loss, MI355X.
// R13: fix R12's spill regression. R12 counters: WRITE_SIZE 80KB -> 156MB,
// FETCH +50MB, VGPR 84 -- __launch_bounds__(NT,3) made the allocator target
// ~84 VGPR and spill ~80 regs of live state to scratch. Keep R12's structure
// (2-plane XQ, register-derived x^2/y^2/xy A-frags, hoisted per channel) but:
//   1. drop the min-waves hint (R11's unhinted build had zero spill at 116);
//   2. move the V-pass weight frags back to LDS reads (2 ds_read_b128/pass,
//      WM still holds the sigma's matrix) -> peak live state ~149 regs,
//      under the 168 line for 3 waves/EU; LDS 47KB allows 3 blocks/CU.
// Everything else identical to R12 (numerically verified).

#define TILE 32
#define HALO 16
#define SSTR 72            // bf16 stride (144B row, 16B-multiple)
#define PLN  (64 * SSTR)
#define PTPLN (32 * SSTR)
#define NT   256

#define C1c 1.0e-4f
#define C2c 9.0e-4f

typedef short bf16x8 __attribute__((ext_vector_type(8)));
typedef float f32x4  __attribute__((ext_vector_type(4)));
typedef unsigned short ush;

// ---- compile-time 1/sum of the 33-tap gaussian ----
constexpr double cexp(double xx) {
  if (xx < -700.0) return 0.0;
  const double ln2 = 0.6931471805599453, il2 = 1.4426950408889634;
  double kd = xx * il2;
  long long k = (long long)(kd + (kd >= 0 ? 0.5 : -0.5));
  double r = xx - (double)k * ln2;
  double t = 1.0, s = 1.0;
  for (int i = 1; i <= 22; ++i) { t *= r / (double)i; s += t; }
  double p = 1.0, base = (k >= 0) ? 2.0 : 0.5;
  long long n = (k >= 0) ? k : -k;
  while (n) { if (n & 1) p *= base; base *= base; n >>= 1; }
  return s * p;
}
constexpr float gsi(double sigma) {
  double inv = 1.0 / (2.0 * sigma * sigma);
  double s = 0.0;
  for (int k = -16; k <= 16; ++k) s += cexp(-(double)(k * k) * inv);
  return (float)(1.0 / s);
}
constexpr float SI05 = gsi(0.5), SI10 = gsi(1.0), SI20 = gsi(2.0),
                SI40 = gsi(4.0), SI80 = gsi(8.0);

// pack two f32 -> bf16x2 (round-half-up)
__device__ __forceinline__ unsigned f2bf_pk(float lo, float hi) {
  union { float f; unsigned u; } a, b; a.f = lo; b.f = hi;
  return __builtin_amdgcn_perm(b.u + 0x8000u, a.u + 0x8000u, 0x07060302u);
}
__device__ __forceinline__ ush f2bf1(float f) {
  union { float f; unsigned u; } c; c.f = f;
  return (ush)((c.u + 0x8000u) >> 16);
}

struct WFrag {
  bf16x8 h[2][2];   // [nt][kchunk] : H-pass B-operand (V-pass frags read from LDS)
};

// Fill WM[m][k] = wf5[SIG][k-m] (k-m in [0,32] else 0), then load H frags.
template<int SIG>
__device__ __forceinline__ void build_wm(ush* __restrict__ WM,
                                         const float (*__restrict__ wf5)[40],
                                         int tid, int wave, int lane,
                                         WFrag& W) {
  __syncthreads();                 // prior WM/frag/PT readers + staged XQ ordered
  #pragma unroll
  for (int i = 0; i < 8; ++i) {
    const int idx = i * 256 + tid;         // 0..2047
    const int m = idx >> 6, k = idx & 63;
    const int t = k - m;
    const int tc = t < 0 ? 0 : (t > 32 ? 32 : t);
    float v = wf5[SIG][tc];
    v = (t >= 0 && t <= 32) ? v : 0.f;
    WM[m * SSTR + k] = f2bf1(v);
  }
  __syncthreads();                 // WM ready
  const int l16 = lane & 15, quad = lane >> 4;
  #pragma unroll
  for (int t = 0; t < 2; ++t)
    #pragma unroll
    for (int c = 0; c < 2; ++c)
      W.h[t][c] = *(const bf16x8*)(WM + (t * 16 + l16) * SSTR + quad * 8 + 32 * c);
}

// One separable conv pass via two banded GEMMs; A-fragments and H-weights
// from registers, V-weights re-read from WM (still valid: WM only written in
// build_wm). Caller must ensure a barrier ordered prior PT readers.
template<int NQ>
__device__ __forceinline__ void conv_pass(const bf16x8 (&A)[NQ][2],
                                          const WFrag& W,
                                          const ush* __restrict__ WM,
                                          ush* __restrict__ PT,
                                          int wave, int lane, f32x4* V) {
  const int l16 = lane & 15, quad = lane >> 4;
  const int m0 = wave * 16;
  // H-GEMM: D(64x32) = A(64x64) x Wh; store transposed bf16 into PT
  #pragma unroll
  for (int q = 0; q < NQ; ++q) {
    #pragma unroll
    for (int nt = 0; nt < 2; ++nt) {
      f32x4 acc = {0.f, 0.f, 0.f, 0.f};
      acc = __builtin_amdgcn_mfma_f32_16x16x32_bf16(A[q][0], W.h[nt][0], acc, 0, 0, 0);
      acc = __builtin_amdgcn_mfma_f32_16x16x32_bf16(A[q][1], W.h[nt][1], acc, 0, 0, 0);
      uint2 u;
      u.x = f2bf_pk(acc[0], acc[1]);
      u.y = f2bf_pk(acc[2], acc[3]);
      *(uint2*)(PT + q * PTPLN + (nt * 16 + l16) * SSTR + m0 + quad * 4) = u;
    }
  }
  // V-pass A-operand (weights) from WM; issue before the barrier so the
  // ds_reads overlap the sync.
  const ush* wvp = WM + ((wave >> 1) * 16 + l16) * SSTR + quad * 8;
  const bf16x8 wv0 = *(const bf16x8*)wvp;
  const bf16x8 wv1 = *(const bf16x8*)(wvp + 32);
  __syncthreads();                 // PT complete
  // V-GEMM: D(32x32) = Wv(32x64) x P
  const int n0 = (wave & 1) * 16;
  #pragma unroll
  for (int q = 0; q < NQ; ++q) {
    const ush* pp = PT + q * PTPLN + (n0 + l16) * SSTR + quad * 8;
    const bf16x8 b0 = *(const bf16x8*)pp;
    const bf16x8 b1 = *(const bf16x8*)(pp + 32);
    f32x4 acc = {0.f, 0.f, 0.f, 0.f};
    acc = __builtin_amdgcn_mfma_f32_16x16x32_bf16(wv0, b0, acc, 0, 0, 0);
    acc = __builtin_amdgcn_mfma_f32_16x16x32_bf16(wv1, b1, acc, 0, 0, 0);
    V[q] = acc;
  }
}

// SSIM epilogue on V[5]
__device__ __forceinline__ void ssim_fold(const f32x4* V, int mult, bool last,
                                          float* PIcs) {
  #pragma unroll
  for (int r = 0; r < 4; ++r) {
    const float mux = V[0][r], muy = V[1][r];
    const float A = mux * muy;
    const float Bq = mux * mux + muy * muy;
    const float S = V[2][r] + V[3][r] - Bq;
    const float sxy = V[4][r] - A;
    const float cs = (2.f * sxy + C2c) * __builtin_amdgcn_rcpf(S + C2c);
    float p = cs;
    if (mult >= 2) p *= cs;
    if (mult >= 3) p *= cs;
    if (last) {
      const float l = (2.f * A + C1c) * __builtin_amdgcn_rcpf(Bq + C1c);
      p *= l * l * l;
    }
    PIcs[r] *= p;
  }
}

__global__ __launch_bounds__(NT)
void msssim_fused_kernel(const float* __restrict__ x, const float* __restrict__ y,
                         const float* __restrict__ disc,
                         float* __restrict__ partials) {
  __shared__ ush XQ[2 * PLN];      // planes: x, y  (plane0 reused for SAD at end)
  __shared__ ush PT[5 * PTPLN];
  __shared__ ush WM[32 * SSTR];
  __shared__ float wf5[5][40];
  __shared__ float red[12];

  const int tid = threadIdx.x;
  const int wave = tid >> 6, lane = tid & 63;
  const int bx = blockIdx.x, by = blockIdx.y, b = blockIdx.z;
  const int x0 = bx * TILE - HALO, y0 = by * TILE - HALO;
  const int blk = (b * 16 + by) * 16 + bx;

  // disc^2 partial (16 elems/block), issued early so latency hides
  float d2 = 0.f;
  { const int di = blk * 16 + tid;
    if (tid < 16 && di < 8 * 62 * 62) { const float dd = disc[di] - 1.f; d2 = dd * dd; } }

  // one-time tap tables (first build_wm's leading barrier orders readers)
  if (tid < 165) {
    const int sig = tid / 33;
    const int k = tid - sig * 33;
    const float d = (float)(k - 16);
    float inv, si;
    if (sig == 0)      { inv = 2.0f;       si = SI05; }
    else if (sig == 1) { inv = 0.5f;       si = SI10; }
    else if (sig == 2) { inv = 0.125f;     si = SI20; }
    else if (sig == 3) { inv = 0.03125f;   si = SI40; }
    else               { inv = 0.0078125f; si = SI80; }
    wf5[sig][k] = __expf(-d * d * inv) * si;
  }

  const int sr = tid >> 4;           // staging row within 16-row band
  const int sc = (tid & 15) * 4;     // staging col group

  float4 PX[4], PY[4];
  auto issue_loads = [&](int ch) {
    const float* __restrict__ xs = x + (size_t)(b * 3 + ch) * 262144;
    const float* __restrict__ ys = y + (size_t)(b * 3 + ch) * 262144;
    #pragma unroll
    for (int it = 0; it < 4; ++it) {
      const int r = it * 16 + sr;
      const int gy = y0 + r, gx = x0 + sc;
      const bool rowok = (gy >= 0) && (gy < 512);
      if (rowok && gx >= 0 && gx <= 508) {
        PX[it] = *(const float4*)(xs + gy * 512 + gx);
        PY[it] = *(const float4*)(ys + gy * 512 + gx);
      } else {
        float tx[4], ty[4];
        #pragma unroll
        for (int e = 0; e < 4; ++e) {
          const int g = gx + e;
          const bool ok = rowok && (g >= 0) && (g < 512);
          tx[e] = ok ? xs[gy * 512 + g] : 0.f;
          ty[e] = ok ? ys[gy * 512 + g] : 0.f;
        }
        PX[it] = make_float4(tx[0], tx[1], tx[2], tx[3]);
        PY[it] = make_float4(ty[0], ty[1], ty[2], ty[3]);
      }
    }
  };

  float PIcs[4] = {1.f, 1.f, 1.f, 1.f};
  float sad[4][4];                    // sum over channels of |x-y|, 16 px/thread
  #pragma unroll
  for (int it = 0; it < 4; ++it)
    #pragma unroll
    for (int e = 0; e < 4; ++e) sad[it][e] = 0.f;

  issue_loads(0);

  // ---- staging helper: 2 planes (x, y) + SAD accumulation ----
  auto stage = [&]() {
    #pragma unroll
    for (int it = 0; it < 4; ++it) {
      const int r = it * 16 + sr;
      float xv[4] = {PX[it].x, PX[it].y, PX[it].z, PX[it].w};
      float yv[4] = {PY[it].x, PY[it].y, PY[it].z, PY[it].w};
      #pragma unroll
      for (int e = 0; e < 4; ++e) {
        xv[e] = fmaf(xv[e], 0.5f, 0.5f);
        yv[e] = fmaf(yv[e], 0.5f, 0.5f);
        sad[it][e] += fabsf(xv[e] - yv[e]);
      }
      const int off = r * SSTR + sc;
      *(uint2*)(XQ + 0 * PLN + off) = make_uint2(f2bf_pk(xv[0], xv[1]), f2bf_pk(xv[2], xv[3]));
      *(uint2*)(XQ + 1 * PLN + off) = make_uint2(f2bf_pk(yv[0], yv[1]), f2bf_pk(yv[2], yv[3]));
    }
  };

  f32x4 V[5];
  WFrag W;
  bf16x8 AF[5][2];   // per-channel A-fragments: x, y, x^2, y^2, xy

  // ---- load x/y A-frags from staged XQ, derive squared planes in regs ----
  // Caller must ensure a barrier ordered the XQ stores before this.
  auto load_derive = [&]() {
    const int l16 = lane & 15, quad = lane >> 4;
    const ush* xp = XQ + (wave * 16 + l16) * SSTR + quad * 8;
    AF[0][0] = *(const bf16x8*)xp;
    AF[0][1] = *(const bf16x8*)(xp + 32);
    AF[1][0] = *(const bf16x8*)(xp + PLN);
    AF[1][1] = *(const bf16x8*)(xp + PLN + 32);
    #pragma unroll
    for (int c = 0; c < 2; ++c) {
      float xf[8], yf[8];
      #pragma unroll
      for (int e = 0; e < 8; ++e) {
        union { unsigned u; float f; } ax, ay;
        ax.u = ((unsigned)(ush)AF[0][c][e]) << 16;
        ay.u = ((unsigned)(ush)AF[1][c][e]) << 16;
        xf[e] = ax.f; yf[e] = ay.f;
      }
      union { unsigned u[4]; bf16x8 v; } w2, w3, w4;
      #pragma unroll
      for (int p = 0; p < 4; ++p) {
        w2.u[p] = f2bf_pk(xf[2*p] * xf[2*p], xf[2*p+1] * xf[2*p+1]);
        w3.u[p] = f2bf_pk(yf[2*p] * yf[2*p], yf[2*p+1] * yf[2*p+1]);
        w4.u[p] = f2bf_pk(xf[2*p] * yf[2*p], xf[2*p+1] * yf[2*p+1]);
      }
      AF[2][c] = w2.v; AF[3][c] = w3.v; AF[4][c] = w4.v;
    }
  };

  // ======== ch0: sigma 0.5 (x3), sigma 1 (x2) ========
  stage();
  issue_loads(1);
  build_wm<0>(WM, wf5, tid, wave, lane, W);     // leading barrier orders XQ too
  load_derive();
  conv_pass<5>(AF, W, WM, PT, wave, lane, V);
  ssim_fold(V, 3, false, PIcs);
  build_wm<1>(WM, wf5, tid, wave, lane, W);
  conv_pass<5>(AF, W, WM, PT, wave, lane, V);   // AF reused
  ssim_fold(V, 2, false, PIcs);

  // ======== ch1: sigma 1 (x1, W reused), sigma 2 (x3), sigma 4 (x1) ======
  stage();
  issue_loads(2);
  __syncthreads();                              // XQ staged; prior PT readers done
  load_derive();
  conv_pass<5>(AF, W, WM, PT, wave, lane, V);
  ssim_fold(V, 1, false, PIcs);
  build_wm<2>(WM, wf5, tid, wave, lane, W);
  conv_pass<5>(AF, W, WM, PT, wave, lane, V);   // AF reused
  ssim_fold(V, 3, false, PIcs);
  build_wm<3>(WM, wf5, tid, wave, lane, W);
  conv_pass<5>(AF, W, WM, PT, wave, lane, V);   // AF reused
  ssim_fold(V, 1, false, PIcs);

  // ======== ch2: sigma 4 (x2, W reused), sigma 8 (x3 + l^3) ========
  stage();
  __syncthreads();                              // XQ staged; prior PT readers done
  load_derive();
  conv_pass<5>(AF, W, WM, PT, wave, lane, V);
  ssim_fold(V, 2, false, PIcs);
  build_wm<4>(WM, wf5, tid, wave, lane, W);
  conv_pass<5>(AF, W, WM, PT, wave, lane, V);   // AF reused
  ssim_fold(V, 3, true, PIcs);

  // ======== deferred gaussian L1: conv(SAD, sigma 8) (W frags reused) ========
  #pragma unroll
  for (int it = 0; it < 4; ++it) {
    const int off = (it * 16 + sr) * SSTR + sc;
    *(uint2*)(XQ + off) =
        make_uint2(f2bf_pk(sad[it][0], sad[it][1]), f2bf_pk(sad[it][2], sad[it][3]));
  }
  __syncthreads();                              // SAD plane staged; PT readers done
  bf16x8 SF[1][2];
  {
    const ush* sp = XQ + (wave * 16 + (lane & 15)) * SSTR + (lane >> 4) * 8;
    SF[0][0] = *(const bf16x8*)sp;
    SF[0][1] = *(const bf16x8*)(sp + 32);
  }
  f32x4 V1[1];
  conv_pass<1>(SF, W, WM, PT, wave, lane, V1);

  // absacc = central sum of SAD regs (rows 16..47 are it=1,2; cols via sc)
  float absacc = 0.f;
  if (sc >= 16 && sc < 48) {
    #pragma unroll
    for (int it = 1; it <= 2; ++it)
      #pragma unroll
      for (int e = 0; e < 4; ++e) absacc += sad[it][e];
  }

  float mixsum = 0.f;
  #pragma unroll
  for (int r = 0; r < 4; ++r) {
    const float ssim = 1.f - PIcs[r];
    mixsum += 200.f * (0.025f * ssim + 0.975f * (V1[0][r] * (1.f / 3.f)));
  }

  #pragma unroll
  for (int off = 32; off > 0; off >>= 1) {
    mixsum += __shfl_down(mixsum, off);
    absacc += __shfl_down(absacc, off);
    d2     += __shfl_down(d2, off);
  }
  if (lane == 0) { red[wave] = mixsum; red[4 + wave] = absacc; red[8 + wave] = d2; }
  __syncthreads();
  if (tid == 0) {
    float m = 0.f, a = 0.f, d = 0.f;
    #pragma unroll
    for (int i = 0; i < 4; ++i) { m += red[i]; a += red[4 + i]; d += red[8 + i]; }
    partials[3 * blk + 0] = m;
    partials[3 * blk + 1] = a;
    partials[3 * blk + 2] = d;
  }
}

__global__ __launch_bounds__(512)
void msssim_final_kernel(const float* __restrict__ partials,
                         float* __restrict__ out) {
  __shared__ float red[24];
  const int tid = threadIdx.x;
  float m = 0.f, a = 0.f, d2 = 0.f;
  for (int j = tid; j < 2048; j += 512) {
    m  += partials[3 * j + 0];
    a  += partials[3 * j + 1];
    d2 += partials[3 * j + 2];
  }
  #pragma unroll
  for (int off = 32; off > 0; off >>= 1) {
    m  += __shfl_down(m, off);
    a  += __shfl_down(a, off);
    d2 += __shfl_down(d2, off);
  }
  const int wave = tid >> 6, lane = tid & 63;
  if (lane == 0) { red[wave] = m; red[8 + wave] = a; red[16 + wave] = d2; }
  __syncthreads();
  if (tid == 0) {
    float sm = 0.f, sa = 0.f, sd = 0.f;
    #pragma unroll
    for (int i = 0; i < 8; ++i) { sm += red[i]; sa += red[8 + i]; sd += red[16 + i]; }
    const float mix_mean  = sm / (8.f * 512.f * 512.f);
    const float abs_mean  = sa / (8.f * 3.f * 512.f * 512.f);
    const float disc_mean = sd / (8.f * 62.f * 62.f);
    out[0] = 0.5f * (mix_mean + 100.f * abs_mean + disc_mean);
  }
}

extern "C" void kernel_launch(void* const* d_in, const int* in_sizes, int n_in,
                              void* d_out, int out_size, void* d_ws, size_t ws_size,
                              hipStream_t stream) {
  const float* x    = (const float*)d_in[0];
  const float* y    = (const float*)d_in[1];
  const float* disc = (const float*)d_in[2];
  // d_in[3] = g_masks (unused: weights recomputed on device)
  float* partials = (float*)d_ws;   // 2048*3 floats, fully overwritten each call
  dim3 grid(16, 16, 8);
  msssim_fused_kernel<<<grid, NT, 0, stream>>>(x, y, disc, partials);
  msssim_final_kernel<<<1, 512, 0, stream>>>(partials, (float*)d_out);
}